// Round 1
// baseline (113.785 us; speedup 1.0000x reference)
//
#include <hip/hip_runtime.h>

// Problem constants (fixed by the reference: N=8192, F=256).
#define NN 8192
#define FF 256

// Kernel 1: per-row dual dot product.
// One 64-lane wave per row; F=256 = 64 lanes x float4.
// left[i] = dot(x[i], W[0:F]) + b ; right[i] = dot(x[i], W[F:2F])
__global__ void row_scores_kernel(const float* __restrict__ x,
                                  const float* __restrict__ W,
                                  const float* __restrict__ b,
                                  float* __restrict__ left,
                                  float* __restrict__ right) {
    const int row  = (int)((blockIdx.x * blockDim.x + threadIdx.x) >> 6);
    const int lane = (int)(threadIdx.x & 63);
    if (row >= NN) return;

    const float4 xv = reinterpret_cast<const float4*>(x + (size_t)row * FF)[lane];
    const float4 wl = reinterpret_cast<const float4*>(W)[lane];
    const float4 wr = reinterpret_cast<const float4*>(W + FF)[lane];

    float l = xv.x * wl.x + xv.y * wl.y + xv.z * wl.z + xv.w * wl.w;
    float r = xv.x * wr.x + xv.y * wr.y + xv.z * wr.z + xv.w * wr.w;

    #pragma unroll
    for (int off = 32; off; off >>= 1) {
        l += __shfl_down(l, off, 64);
        r += __shfl_down(r, off, 64);
    }
    if (lane == 0) {
        left[row]  = l + b[0];
        right[row] = r;
    }
}

// Kernel 2: out[i,j] = adj[i,j] * sigmoid(left[i] + right[j])
// Pure streaming pass: float4 per thread, grid-stride. HBM-bound.
__global__ void att_kernel(const float* __restrict__ adj,
                           const float* __restrict__ left,
                           const float* __restrict__ right,
                           float* __restrict__ out) {
    const unsigned total4 = (unsigned)NN * (NN / 4);   // 16,777,216 float4s
    const unsigned stride = gridDim.x * blockDim.x;
    const float4* __restrict__ adj4   = reinterpret_cast<const float4*>(adj);
    const float4* __restrict__ right4 = reinterpret_cast<const float4*>(right);
    float4* __restrict__ out4         = reinterpret_cast<float4*>(out);

    for (unsigned idx = blockIdx.x * blockDim.x + threadIdx.x; idx < total4; idx += stride) {
        const unsigned i  = idx >> 11;      // NN/4 = 2048 = 2^11 float4s per row
        const unsigned j4 = idx & 2047u;

        const float  li = left[i];          // wave-uniform within a row span -> cached broadcast
        const float4 r4 = right4[j4];       // 32 KB table -> L1/L2 resident
        const float4 a4 = adj4[idx];        // streaming, coalesced

        float4 o;
        o.x = a4.x * (1.0f / (1.0f + __expf(-(li + r4.x))));
        o.y = a4.y * (1.0f / (1.0f + __expf(-(li + r4.y))));
        o.z = a4.z * (1.0f / (1.0f + __expf(-(li + r4.z))));
        o.w = a4.w * (1.0f / (1.0f + __expf(-(li + r4.w))));
        out4[idx] = o;
    }
}

extern "C" void kernel_launch(void* const* d_in, const int* in_sizes, int n_in,
                              void* d_out, int out_size, void* d_ws, size_t ws_size,
                              hipStream_t stream) {
    const float* x   = (const float*)d_in[0];   // [N, F]
    const float* adj = (const float*)d_in[1];   // [N, N]
    const float* W   = (const float*)d_in[2];   // [2F, 1]
    const float* b   = (const float*)d_in[3];   // [1]
    float* out = (float*)d_out;                 // [N, N]

    float* left  = (float*)d_ws;                // N floats
    float* right = left + NN;                   // N floats

    // Kernel 1: 8192 waves = 524288 threads -> 2048 blocks of 256.
    row_scores_kernel<<<dim3((NN * 64) / 256), dim3(256), 0, stream>>>(x, W, b, left, right);

    // Kernel 2: 2048 blocks x 256 threads, grid-stride (32 float4 iters/thread).
    att_kernel<<<dim3(2048), dim3(256), 0, stream>>>(adj, left, right, out);
}